// Round 13
// baseline (232.138 us; speedup 1.0000x reference)
//
#include <hip/hip_runtime.h>
#include <float.h>
#include <limits.h>
#include <math.h>

namespace {

constexpr int NB = 8;
constexpr int SL = 2048;
constexpr int DIM = 128;
constexpr int PP = 64;
constexpr int KK = 64;
constexpr int ROWS = 128;                // score tile rows
constexpr int CTILE = 128;               // score tile cols
constexpr int NSTRIP = SL / ROWS;        // 16
constexpr int CSPLIT = 8;                // col eighths -> 1024 blocks, ~512 useful (2/CU)
constexpr int NSLOT = NSTRIP * CSPLIT;   // 128 slots per batch
constexpr int CAP = 512;                 // per-block candidate buffer
constexpr int PROJ_ROWS = 32;            // rows per proj block
constexpr int NPROJ = NB * SL / PROJ_ROWS;  // 512 proj blocks
constexpr float MARGIN = 4e-3f;          // >> 2x worst-case fp32 dot error

__device__ __forceinline__ bool cgt64(double v1, int i1, double v2, int i2) {
  return (v1 > v2) || (v1 == v2 && i1 < i2);
}
__device__ __forceinline__ bool cgt32(float v1, int i1, float v2, int i2) {
  return (v1 > v2) || (v1 == v2 && i1 < i2);
}

// R12-VERIFIED VERBATIM. Blocks [0,NPROJ): Q/K projection, 32 rows/block,
// W staged once in LDS; fp64 chains bit-identical to R10/R11 proj.
// Blocks [NPROJ, NPROJ+NB): mask canonicalize + compact.
__global__ __launch_bounds__(256) void proj_compact_kernel(
    const float* __restrict__ x, const void* __restrict__ mask_raw,
    const float* __restrict__ Wq, const float* __restrict__ bq,
    const float* __restrict__ Wk, const float* __restrict__ bk,
    float* __restrict__ Q, float* __restrict__ K,
    int* __restrict__ pos, int* __restrict__ cnt) {
  const int tid = threadIdx.x;
  if (blockIdx.x >= NPROJ) {
    const int b = blockIdx.x - NPROJ;
    const int lane = tid & 63, wid = tid >> 6;
    __shared__ int bytemode;
    __shared__ int wsum[4];
    if (tid == 0) bytemode = 0;
    __syncthreads();
    const unsigned char* allb = (const unsigned char*)mask_raw;
    int local = 0;
    for (int t = tid; t < 512; t += 256)
      if ((t & 3) != 0 && allb[t] != 0) local = 1;   // dtype probe
    if (local) atomicOr(&bytemode, 1);
    __syncthreads();
    int f[8]; int c = 0;
    const int base = tid * 8;
    if (bytemode) {
      const unsigned char* p = allb + (size_t)b * SL;
      for (int j = 0; j < 8; ++j) { f[j] = p[base + j] ? 1 : 0; c += f[j]; }
    } else {
      const int* p = (const int*)mask_raw + (size_t)b * SL;
      for (int j = 0; j < 8; ++j) { f[j] = p[base + j] ? 1 : 0; c += f[j]; }
    }
    int incl = c;
    for (int off = 1; off < 64; off <<= 1) {
      int t = __shfl_up(incl, off);
      if (lane >= off) incl += t;
    }
    if (lane == 63) wsum[wid] = incl;
    __syncthreads();
    int woff = 0;
    for (int w = 0; w < wid; ++w) woff += wsum[w];
    int k = woff + incl - c;
    for (int j = 0; j < 8; ++j)
      if (f[j]) pos[b * SL + (k++)] = base + j;
    if (tid == 255) cnt[b] = k;
    return;
  }
  __shared__ __align__(16) float sWq[DIM * PP];  // 32 KB
  __shared__ __align__(16) float sWk[DIM * PP];  // 32 KB
  __shared__ float sx[8 * DIM];                  // 4 KB
  for (int t = tid; t < DIM * PP / 4; t += 256) {
    ((float4*)sWq)[t] = ((const float4*)Wq)[t];
    ((float4*)sWk)[t] = ((const float4*)Wk)[t];
  }
  const int row0 = blockIdx.x * PROJ_ROWS;
  const int r = tid >> 5;
  const int pp = (tid & 31) * 2;
  for (int g = 0; g < PROJ_ROWS / 8; ++g) {
    __syncthreads();  // g=0: W staged; g>0: prior readers of sx done
    for (int t = tid; t < 8 * DIM; t += 256)
      sx[t] = x[(size_t)(row0 + g * 8) * DIM + t];
    __syncthreads();
    double aq0 = 0, aq1 = 0, ak0 = 0, ak1 = 0;
    double cq0 = 0, cq1 = 0, ck0 = 0, ck1 = 0;
    const float* xr = &sx[r * DIM];
    for (int d = 0; d < DIM; d += 2) {
      const double x0 = (double)xr[d], x1 = (double)xr[d + 1];
      const float2 wq0 = *(const float2*)&sWq[d * PP + pp];
      const float2 wq1 = *(const float2*)&sWq[(d + 1) * PP + pp];
      const float2 wk0 = *(const float2*)&sWk[d * PP + pp];
      const float2 wk1 = *(const float2*)&sWk[(d + 1) * PP + pp];
      aq0 += x0 * (double)wq0.x; aq1 += x0 * (double)wq0.y;
      cq0 += x1 * (double)wq1.x; cq1 += x1 * (double)wq1.y;
      ak0 += x0 * (double)wk0.x; ak1 += x0 * (double)wk0.y;
      ck0 += x1 * (double)wk1.x; ck1 += x1 * (double)wk1.y;
    }
    const size_t o = ((size_t)row0 + g * 8 + r) * PP + pp;
    Q[o]     = (float)(aq0 + cq0 + (double)bq[pp]);
    Q[o + 1] = (float)(aq1 + cq1 + (double)bq[pp + 1]);
    K[o]     = (float)(ak0 + ck0 + (double)bk[pp]);
    K[o + 1] = (float)(ak1 + ck1 + (double)bk[pp + 1]);
  }
}

// R11/R12-VERIFIED body; only CSPLIT (grid split) changed 4->8 so ~512 useful
// blocks run 2/CU and serial tails overlap across resident blocks.
__global__ __launch_bounds__(256, 2) void score_kernel(
    const float* __restrict__ Q, const float* __restrict__ K,
    const int* __restrict__ pos, const int* __restrict__ cnt,
    double* __restrict__ chunk_val, int* __restrict__ chunk_idx) {
  __shared__ __align__(16) float sQ[128 * 68];   // aliased by rval after scoring
  __shared__ __align__(16) float sK[128 * 68];
  __shared__ float cval[CAP];
  __shared__ int cidx[CAP];
  __shared__ float smax[256];
  __shared__ int spos_r[ROWS], spos_c[CTILE];
  __shared__ int cnt_sh, ovf, mcnt;
  __shared__ float thresh;

  const int b = blockIdx.z, strip = blockIdx.x, colq = blockIdx.y;
  const int tid = threadIdx.x, lane = tid & 63;
  const int nv = cnt[b];
  const int slot = (b * NSTRIP + strip) * CSPLIT + colq;
  const int r0 = strip * ROWS;
  const int per = (nv + CSPLIT - 1) / CSPLIT;
  const int cbeg = colq * per;
  const int cend = min(cbeg + per, nv);
  double* chv = chunk_val + (size_t)slot * KK;
  int* chi = chunk_idx + (size_t)slot * KK;
  if (r0 >= nv || cbeg >= cend) {
    if (tid < KK) { chv[tid] = -DBL_MAX; chi[tid] = INT_MAX; }
    return;
  }
  const int nrows = min(ROWS, nv - r0);
  if (tid < ROWS) spos_r[tid] = (tid < nrows) ? pos[b * SL + r0 + tid] : 0;
  for (int t = tid; t < 128 * 16; t += 256) {
    const int row = t >> 4, p4 = t & 15;
    float4 v = make_float4(0.f, 0.f, 0.f, 0.f);
    if (row < nrows) {
      const int g = pos[b * SL + r0 + row];
      v = *(const float4*)(Q + ((size_t)b * SL + g) * PP + p4 * 4);
    }
    *(float4*)&sQ[row * 68 + p4 * 4] = v;
  }
  if (tid == 0) { cnt_sh = 0; ovf = 0; thresh = -FLT_MAX; }
  __syncthreads();

  const int ry = tid & 15, cy = tid >> 4;   // rows ry+16i, cols cy+16j (i,j<8)

  for (int c0 = cbeg; c0 < cend; c0 += CTILE) {
    const int ncols = min(CTILE, cend - c0);
    if (tid < CTILE) spos_c[tid] = (tid < ncols) ? pos[b * SL + c0 + tid] : 0;
    for (int t = tid; t < 128 * 16; t += 256) {
      const int col = t >> 4, p4 = t & 15;
      float4 v = make_float4(0.f, 0.f, 0.f, 0.f);
      if (col < ncols) {
        const int g = pos[b * SL + c0 + col];
        v = *(const float4*)(K + ((size_t)b * SL + g) * PP + p4 * 4);
      }
      *(float4*)&sK[col * 68 + p4 * 4] = v;
    }
    __syncthreads();

    float acc[8][8] = {};
    for (int p4 = 0; p4 < 16; ++p4) {
      float4 qv[8], kv[8];
#pragma unroll
      for (int i = 0; i < 8; ++i) qv[i] = *(const float4*)&sQ[(ry + 16 * i) * 68 + p4 * 4];
#pragma unroll
      for (int j = 0; j < 8; ++j) kv[j] = *(const float4*)&sK[(cy + 16 * j) * 68 + p4 * 4];
#pragma unroll
      for (int i = 0; i < 8; ++i)
#pragma unroll
        for (int j = 0; j < 8; ++j) {
          acc[i][j] = fmaf(qv[i].x, kv[j].x, acc[i][j]);
          acc[i][j] = fmaf(qv[i].y, kv[j].y, acc[i][j]);
          acc[i][j] = fmaf(qv[i].z, kv[j].z, acc[i][j]);
          acc[i][j] = fmaf(qv[i].w, kv[j].w, acc[i][j]);
        }
    }

    if (c0 == cbeg) {
      // ---- self-seed threshold from tile 0 (verified construction) ----
      float tmax = -FLT_MAX;
      for (int i = 0; i < 8; ++i) {
        const int rr = ry + 16 * i;
        if (rr >= nrows) continue;
        for (int j = 0; j < 8; ++j) {
          const int cc = cy + 16 * j;
          if (cc >= ncols) continue;
          tmax = fmaxf(tmax, acc[i][j] * 0.125f);
        }
      }
      smax[tid] = tmax;
      __syncthreads();
      for (int k2 = 2; k2 <= 256; k2 <<= 1)
        for (int j2 = k2 >> 1; j2 >= 1; j2 >>= 1) {
          if (tid < 128) {
            const int i = ((tid & ~(j2 - 1)) << 1) | (tid & (j2 - 1));
            const int p = i | j2;
            const bool desc = ((i & k2) == 0);
            const float vi = smax[i], vp = smax[p];
            const bool sw = desc ? (vp > vi) : (vi > vp);
            if (sw) { smax[i] = vp; smax[p] = vi; }
          }
          __syncthreads();
        }
      if (tid == 0 && smax[KK - 1] > -FLT_MAX) thresh = smax[KK - 1] - MARGIN;
      __syncthreads();
    }

    // wave-granular all-or-nothing emission; overflow -> compact + retry
    bool pushed = false;
    for (int attempt = 0; attempt < 8; ++attempt) {
      const float th = thresh;
      int nloc = 0;
      for (int i = 0; i < 8; ++i) {
        const int rr = ry + 16 * i;
        if (rr >= nrows) continue;
        for (int j = 0; j < 8; ++j) {
          const int cc = cy + 16 * j;
          if (cc >= ncols) continue;
          if (acc[i][j] * 0.125f >= th) nloc++;
        }
      }
      int incl = nloc;
      for (int off = 1; off < 64; off <<= 1) {
        int t2 = __shfl_up(incl, off);
        if (lane >= off) incl += t2;
      }
      const int wtot = __shfl(incl, 63);
      if (!pushed) {
        if (wtot == 0) {
          pushed = true;
        } else {
          int wbase = 0;
          if (lane == 63) {
            wbase = atomicAdd(&cnt_sh, wtot);
            if (wbase + wtot > CAP) { atomicAdd(&cnt_sh, -wtot); wbase = -1; ovf = 1; }
          }
          wbase = __shfl(wbase, 63);
          if (wbase >= 0) {
            int sl = wbase + incl - nloc;
            for (int i = 0; i < 8; ++i) {
              const int rr = ry + 16 * i;
              if (rr >= nrows) continue;
              for (int j = 0; j < 8; ++j) {
                const int cc = cy + 16 * j;
                if (cc >= ncols) continue;
                const float s = acc[i][j] * 0.125f;
                if (s >= th) {
                  cval[sl] = s;
                  cidx[sl] = spos_r[rr] * SL + spos_c[cc];
                  ++sl;
                }
              }
            }
            pushed = true;
          }
        }
      }
      __syncthreads();
      if (ovf == 0) break;
      // ---- compaction (cold path, verified): sort fp32 buffer, raise thresh ----
      {
        const int n = cnt_sh;
        for (int j = n + tid; j < CAP; j += 256) { cval[j] = -FLT_MAX; cidx[j] = INT_MAX; }
        __syncthreads();
        for (int k2 = 2; k2 <= CAP; k2 <<= 1)
          for (int j2 = k2 >> 1; j2 >= 1; j2 >>= 1) {
            const int i = ((tid & ~(j2 - 1)) << 1) | (tid & (j2 - 1));
            const int p = i | j2;
            const bool desc = ((i & k2) == 0);
            const float vi = cval[i], vp = cval[p];
            const int ii = cidx[i], ip = cidx[p];
            const bool sw = desc ? cgt32(vp, ip, vi, ii) : cgt32(vi, ii, vp, ip);
            if (sw) { cval[i] = vp; cidx[i] = ip; cval[p] = vi; cidx[p] = ii; }
            __syncthreads();
          }
        const float t64 = cval[KK - 1];
        const float nth = (t64 > -FLT_MAX) ? (t64 - MARGIN) : thresh;
        for (int j = tid; j < CAP; j += 256) {
          const bool in = (cidx[j] != INT_MAX) && (cval[j] >= nth);
          const bool nx = (j + 1 < CAP) && (cidx[j + 1] != INT_MAX) && (cval[j + 1] >= nth);
          if (in && !nx) mcnt = j + 1;
          if (j == 0 && !in) mcnt = 0;
        }
        __syncthreads();
        if (tid == 0) { thresh = nth; cnt_sh = mcnt; ovf = 0; }
        __syncthreads();
      }
    }
    __syncthreads();  // protect sK/spos_c restage
  }

  // ---- fp64 refine (8 threads/survivor, verified) ----
  const int n = cnt_sh;
  double* rval = (double*)sQ;  // alias: sQ dead after scoring
  for (int base2 = 0; base2 < n; base2 += 32) {
    const int s = base2 + (tid >> 3);
    double p = 0;
    if (s < n) {
      const int fi = cidx[s];
      const int orow = fi >> 11, ocol = fi & (SL - 1);
      const float* qr = Q + ((size_t)b * SL + orow) * PP + (tid & 7) * 8;
      const float* kr = K + ((size_t)b * SL + ocol) * PP + (tid & 7) * 8;
#pragma unroll
      for (int e = 0; e < 8; ++e) p = fma((double)qr[e], (double)kr[e], p);
    }
    p += __shfl_down(p, 4);
    p += __shfl_down(p, 2);
    p += __shfl_down(p, 1);
    if (((tid & 7) == 0) && s < n) rval[s] = p * 0.125;
  }
  // ---- adaptive LDS bitonic (verified) + top-64 out ----
  int np2 = KK;
  while (np2 < n) np2 <<= 1;  // n <= CAP
  for (int j = n + tid; j < np2; j += 256) { rval[j] = -DBL_MAX; cidx[j] = INT_MAX; }
  __syncthreads();
  for (int k2 = 2; k2 <= np2; k2 <<= 1)
    for (int j2 = k2 >> 1; j2 >= 1; j2 >>= 1) {
      if (tid < (np2 >> 1)) {
        const int i = ((tid & ~(j2 - 1)) << 1) | (tid & (j2 - 1));
        const int p = i | j2;
        const bool desc = ((i & k2) == 0);
        const double vi = rval[i], vp = rval[p];
        const int ii = cidx[i], ip = cidx[p];
        const bool sw = desc ? cgt64(vp, ip, vi, ii) : cgt64(vi, ii, vp, ip);
        if (sw) { rval[i] = vp; cidx[i] = ip; rval[p] = vi; cidx[p] = ii; }
      }
      __syncthreads();
    }
  if (tid < KK) { chv[tid] = rval[tid]; chi[tid] = cidx[tid]; }
}

// R10-VERIFIED VERBATIM (NSLOT=128, 2 lists/lane): 128-way merge of sorted
// lists (heads staged 16-deep in LDS), fp64 softmax, outputs.
__global__ __launch_bounds__(256) void merge_kernel(
    const double* __restrict__ chunk_val, const int* __restrict__ chunk_idx,
    float* __restrict__ out) {
  __shared__ double sval[NSLOT * 16];
  __shared__ int sidx[NSLOT * 16];
  const int b = blockIdx.x, tid = threadIdx.x;
  const double* vb = chunk_val + (size_t)b * NSLOT * KK;
  const int* ib = chunk_idx + (size_t)b * NSLOT * KK;
  for (int t = tid; t < NSLOT * 16; t += 256) {
    const int list = t >> 4, e = t & 15;
    sval[t] = vb[list * KK + e];
    sidx[t] = ib[list * KK + e];
  }
  __syncthreads();
  if (tid < 64) {
    const int lane = tid;
    double cur[2]; int curi[2]; int hp[2];
    for (int l = 0; l < 2; ++l) {
      const int list = lane * 2 + l;
      hp[l] = 0;
      cur[l] = sval[list * 16];
      curi[l] = sidx[list * 16];
    }
    double myv = -DBL_MAX; int myi = INT_MAX;
    for (int k = 0; k < KK; ++k) {
      double bv = cur[0]; int bi = curi[0]; int bl = 0;
      if (cgt64(cur[1], curi[1], bv, bi)) { bv = cur[1]; bi = curi[1]; bl = 1; }
      int bg = lane * 2 + bl;
      for (int off2 = 32; off2 > 0; off2 >>= 1) {
        const double v2 = __shfl_down(bv, off2);
        const int i2 = __shfl_down(bi, off2);
        const int g2 = __shfl_down(bg, off2);
        if (cgt64(v2, i2, bv, bi)) { bv = v2; bi = i2; bg = g2; }
      }
      bv = __shfl(bv, 0); bi = __shfl(bi, 0); bg = __shfl(bg, 0);
      if ((bg >> 1) == lane) {
        const int l = bg & 1;
        const int h = ++hp[l];
        if (h < 16) { cur[l] = sval[bg * 16 + h]; curi[l] = sidx[bg * 16 + h]; }
        else if (h < KK) { cur[l] = vb[bg * KK + h]; curi[l] = ib[bg * KK + h]; }
        else { cur[l] = -DBL_MAX; curi[l] = INT_MAX; }
      }
      if (lane == k) { myv = bv; myi = bi; }
    }
    const double m = __shfl(myv, 0);
    double e = (myi == INT_MAX || myv == -DBL_MAX) ? 0.0 : exp(myv - m);
    double s = e;
    for (int off2 = 32; off2 > 0; off2 >>= 1) s += __shfl_down(s, off2);
    s = __shfl(s, 0);
    if (s <= 0.0) s = 1.0;
    const double w = e / s;
    int row = 0, col = 0;
    if (myi != INT_MAX) { row = myi >> 11; col = myi & (SL - 1); }
    float* oidx = out;
    float* owt = out + (size_t)NB * KK * 2;
    oidx[((size_t)b * KK + lane) * 2 + 0] = (float)row;
    oidx[((size_t)b * KK + lane) * 2 + 1] = (float)col;
    owt[(size_t)b * KK + lane] = (float)w;
  }
}

}  // namespace

extern "C" void kernel_launch(void* const* d_in, const int* in_sizes, int n_in,
                              void* d_out, int out_size, void* d_ws, size_t ws_size,
                              hipStream_t stream) {
  const float* x = (const float*)d_in[0];
  const void* mask_raw = d_in[1];
  const float* Wq = (const float*)d_in[2];
  const float* bq = (const float*)d_in[3];
  const float* Wk = (const float*)d_in[4];
  const float* bk = (const float*)d_in[5];
  float* out = (float*)d_out;

  char* ws = (char*)d_ws;
  const size_t qk = (size_t)NB * SL * PP;  // 1,048,576 elems
  float* Q = (float*)ws;                                            // 4 MB
  float* K = (float*)(ws + qk * 4);                                 // 4 MB
  size_t off = qk * 8;
  double* chunk_val = (double*)(ws + off); off += (size_t)NB * NSLOT * KK * 8;  // 512 KB
  int* chunk_idx = (int*)(ws + off);       off += (size_t)NB * NSLOT * KK * 4;  // 256 KB
  int* pos = (int*)(ws + off);             off += (size_t)NB * SL * 4;          // 64 KB
  int* cntv = (int*)(ws + off);            // total ~8.8 MB

  proj_compact_kernel<<<NPROJ + NB, 256, 0, stream>>>(
      x, mask_raw, Wq, bq, Wk, bk, Q, K, pos, cntv);
  score_kernel<<<dim3(NSTRIP, CSPLIT, NB), 256, 0, stream>>>(
      Q, K, pos, cntv, chunk_val, chunk_idx);
  merge_kernel<<<NB, 256, 0, stream>>>(chunk_val, chunk_idx, out);
}

// Round 14
// 208.380 us; speedup vs baseline: 1.1140x; 1.1140x over previous
//
#include <hip/hip_runtime.h>
#include <float.h>
#include <limits.h>
#include <math.h>

namespace {

constexpr int NB = 8;
constexpr int SL = 2048;
constexpr int DIM = 128;
constexpr int PP = 64;
constexpr int KK = 64;
constexpr int ROWS = 128;                // score tile rows
constexpr int CTILE = 128;               // score tile cols
constexpr int NSTRIP = SL / ROWS;        // 16
constexpr int CSPLIT = 4;                // R12-verified best (8 regressed: no 2nd resident block)
constexpr int NSLOT = NSTRIP * CSPLIT;   // 64 slots per batch
constexpr int CAP = 512;                 // per-block candidate buffer
constexpr int PROJ_ROWS = 32;            // rows per proj block
constexpr int NPROJ = NB * SL / PROJ_ROWS;  // 512 proj blocks
constexpr float MARGIN = 4e-3f;          // >> 2x worst-case fp32 dot error

__device__ __forceinline__ bool cgt64(double v1, int i1, double v2, int i2) {
  return (v1 > v2) || (v1 == v2 && i1 < i2);
}
__device__ __forceinline__ bool cgt32(float v1, int i1, float v2, int i2) {
  return (v1 > v2) || (v1 == v2 && i1 < i2);
}

// Blocks [0,NPROJ): Q/K projection, 32 rows/block, W+x staged once in LDS.
// REGISTER-BLOCKED 4 rows/thread: cuts LDS issue ~8x vs R12 (R12 proj was
// LDS-issue-bound ~60 us: 3072 LDS insts/wave). Per-output fp64 math is
// BIT-IDENTICAL to R10/R11/R12 (same even/odd-d chains in the same order,
// same (a+c)+bias finish, same w/x element addresses).
// Blocks [NPROJ, NPROJ+NB): mask canonicalize + compact (verified).
__global__ __launch_bounds__(256) void proj_compact_kernel(
    const float* __restrict__ x, const void* __restrict__ mask_raw,
    const float* __restrict__ Wq, const float* __restrict__ bq,
    const float* __restrict__ Wk, const float* __restrict__ bk,
    float* __restrict__ Q, float* __restrict__ K,
    int* __restrict__ pos, int* __restrict__ cnt) {
  const int tid = threadIdx.x;
  if (blockIdx.x >= NPROJ) {
    const int b = blockIdx.x - NPROJ;
    const int lane = tid & 63, wid = tid >> 6;
    __shared__ int bytemode;
    __shared__ int wsum[4];
    if (tid == 0) bytemode = 0;
    __syncthreads();
    const unsigned char* allb = (const unsigned char*)mask_raw;
    int local = 0;
    for (int t = tid; t < 512; t += 256)
      if ((t & 3) != 0 && allb[t] != 0) local = 1;   // dtype probe
    if (local) atomicOr(&bytemode, 1);
    __syncthreads();
    int f[8]; int c = 0;
    const int base = tid * 8;
    if (bytemode) {
      const unsigned char* p = allb + (size_t)b * SL;
      for (int j = 0; j < 8; ++j) { f[j] = p[base + j] ? 1 : 0; c += f[j]; }
    } else {
      const int* p = (const int*)mask_raw + (size_t)b * SL;
      for (int j = 0; j < 8; ++j) { f[j] = p[base + j] ? 1 : 0; c += f[j]; }
    }
    int incl = c;
    for (int off = 1; off < 64; off <<= 1) {
      int t = __shfl_up(incl, off);
      if (lane >= off) incl += t;
    }
    if (lane == 63) wsum[wid] = incl;
    __syncthreads();
    int woff = 0;
    for (int w = 0; w < wid; ++w) woff += wsum[w];
    int k = woff + incl - c;
    for (int j = 0; j < 8; ++j)
      if (f[j]) pos[b * SL + (k++)] = base + j;
    if (tid == 255) cnt[b] = k;
    return;
  }
  __shared__ __align__(16) float sWq[DIM * PP];      // 32 KB
  __shared__ __align__(16) float sWk[DIM * PP];      // 32 KB
  __shared__ __align__(16) float sx[PROJ_ROWS * DIM];  // 16 KB
  for (int t = tid; t < DIM * PP / 4; t += 256) {
    ((float4*)sWq)[t] = ((const float4*)Wq)[t];
    ((float4*)sWk)[t] = ((const float4*)Wk)[t];
  }
  const int row0 = blockIdx.x * PROJ_ROWS;
  for (int t = tid; t < PROJ_ROWS * 32; t += 256) {
    const int row = t >> 5, f = t & 31;
    *(float4*)&sx[row * DIM + f * 4] =
        *(const float4*)(x + (size_t)(row0 + row) * DIM + f * 4);
  }
  __syncthreads();
  const int rq = tid >> 5;        // 8 row-quads: rows rq*4 .. rq*4+3
  const int pp = (tid & 31) * 2;  // same col-pair mapping as R12
  // [row][col][parity]: a=even-d chain, c=odd-d chain — identical chain
  // structure to R12's aq0/cq0 etc., now 4 rows per thread.
  double aq[4][2] = {}, cq[4][2] = {}, ak[4][2] = {}, ck[4][2] = {};
  for (int d = 0; d < DIM; d += 4) {
    float4 xv[4];
#pragma unroll
    for (int i = 0; i < 4; ++i)
      xv[i] = *(const float4*)&sx[(rq * 4 + i) * DIM + d];
    const float2 wq0 = *(const float2*)&sWq[(d + 0) * PP + pp];
    const float2 wq1 = *(const float2*)&sWq[(d + 1) * PP + pp];
    const float2 wq2 = *(const float2*)&sWq[(d + 2) * PP + pp];
    const float2 wq3 = *(const float2*)&sWq[(d + 3) * PP + pp];
    const float2 wk0 = *(const float2*)&sWk[(d + 0) * PP + pp];
    const float2 wk1 = *(const float2*)&sWk[(d + 1) * PP + pp];
    const float2 wk2 = *(const float2*)&sWk[(d + 2) * PP + pp];
    const float2 wk3 = *(const float2*)&sWk[(d + 3) * PP + pp];
#pragma unroll
    for (int i = 0; i < 4; ++i) {
      const double x0 = (double)xv[i].x, x1 = (double)xv[i].y;
      const double x2 = (double)xv[i].z, x3 = (double)xv[i].w;
      // even chain: d, d+2 (in order); odd chain: d+1, d+3 (in order) —
      // exactly the term order of R12's d-step-2 loop.
      aq[i][0] += x0 * (double)wq0.x; aq[i][1] += x0 * (double)wq0.y;
      cq[i][0] += x1 * (double)wq1.x; cq[i][1] += x1 * (double)wq1.y;
      aq[i][0] += x2 * (double)wq2.x; aq[i][1] += x2 * (double)wq2.y;
      cq[i][0] += x3 * (double)wq3.x; cq[i][1] += x3 * (double)wq3.y;
      ak[i][0] += x0 * (double)wk0.x; ak[i][1] += x0 * (double)wk0.y;
      ck[i][0] += x1 * (double)wk1.x; ck[i][1] += x1 * (double)wk1.y;
      ak[i][0] += x2 * (double)wk2.x; ak[i][1] += x2 * (double)wk2.y;
      ck[i][0] += x3 * (double)wk3.x; ck[i][1] += x3 * (double)wk3.y;
    }
  }
  const double b0q = (double)bq[pp], b1q = (double)bq[pp + 1];
  const double b0k = (double)bk[pp], b1k = (double)bk[pp + 1];
#pragma unroll
  for (int i = 0; i < 4; ++i) {
    const size_t o = ((size_t)row0 + rq * 4 + i) * PP + pp;
    Q[o]     = (float)(aq[i][0] + cq[i][0] + b0q);
    Q[o + 1] = (float)(aq[i][1] + cq[i][1] + b1q);
    K[o]     = (float)(ak[i][0] + ck[i][0] + b0k);
    K[o + 1] = (float)(ak[i][1] + ck[i][1] + b1k);
  }
}

// R12-VERIFIED VERBATIM. Per (batch, 128-row strip, col quarter): fp32 scores
// with 8x8 strided micro-tile; self-seeded threshold from tile 0; emission /
// overflow-compaction / fp64 refine / adaptive bitonic.
__global__ __launch_bounds__(256, 2) void score_kernel(
    const float* __restrict__ Q, const float* __restrict__ K,
    const int* __restrict__ pos, const int* __restrict__ cnt,
    double* __restrict__ chunk_val, int* __restrict__ chunk_idx) {
  __shared__ __align__(16) float sQ[128 * 68];   // aliased by rval after scoring
  __shared__ __align__(16) float sK[128 * 68];
  __shared__ float cval[CAP];
  __shared__ int cidx[CAP];
  __shared__ float smax[256];
  __shared__ int spos_r[ROWS], spos_c[CTILE];
  __shared__ int cnt_sh, ovf, mcnt;
  __shared__ float thresh;

  const int b = blockIdx.z, strip = blockIdx.x, colq = blockIdx.y;
  const int tid = threadIdx.x, lane = tid & 63;
  const int nv = cnt[b];
  const int slot = (b * NSTRIP + strip) * CSPLIT + colq;
  const int r0 = strip * ROWS;
  const int per = (nv + CSPLIT - 1) / CSPLIT;
  const int cbeg = colq * per;
  const int cend = min(cbeg + per, nv);
  double* chv = chunk_val + (size_t)slot * KK;
  int* chi = chunk_idx + (size_t)slot * KK;
  if (r0 >= nv || cbeg >= cend) {
    if (tid < KK) { chv[tid] = -DBL_MAX; chi[tid] = INT_MAX; }
    return;
  }
  const int nrows = min(ROWS, nv - r0);
  if (tid < ROWS) spos_r[tid] = (tid < nrows) ? pos[b * SL + r0 + tid] : 0;
  for (int t = tid; t < 128 * 16; t += 256) {
    const int row = t >> 4, p4 = t & 15;
    float4 v = make_float4(0.f, 0.f, 0.f, 0.f);
    if (row < nrows) {
      const int g = pos[b * SL + r0 + row];
      v = *(const float4*)(Q + ((size_t)b * SL + g) * PP + p4 * 4);
    }
    *(float4*)&sQ[row * 68 + p4 * 4] = v;
  }
  if (tid == 0) { cnt_sh = 0; ovf = 0; thresh = -FLT_MAX; }
  __syncthreads();

  const int ry = tid & 15, cy = tid >> 4;   // rows ry+16i, cols cy+16j (i,j<8)

  for (int c0 = cbeg; c0 < cend; c0 += CTILE) {
    const int ncols = min(CTILE, cend - c0);
    if (tid < CTILE) spos_c[tid] = (tid < ncols) ? pos[b * SL + c0 + tid] : 0;
    for (int t = tid; t < 128 * 16; t += 256) {
      const int col = t >> 4, p4 = t & 15;
      float4 v = make_float4(0.f, 0.f, 0.f, 0.f);
      if (col < ncols) {
        const int g = pos[b * SL + c0 + col];
        v = *(const float4*)(K + ((size_t)b * SL + g) * PP + p4 * 4);
      }
      *(float4*)&sK[col * 68 + p4 * 4] = v;
    }
    __syncthreads();

    float acc[8][8] = {};
    for (int p4 = 0; p4 < 16; ++p4) {
      float4 qv[8], kv[8];
#pragma unroll
      for (int i = 0; i < 8; ++i) qv[i] = *(const float4*)&sQ[(ry + 16 * i) * 68 + p4 * 4];
#pragma unroll
      for (int j = 0; j < 8; ++j) kv[j] = *(const float4*)&sK[(cy + 16 * j) * 68 + p4 * 4];
#pragma unroll
      for (int i = 0; i < 8; ++i)
#pragma unroll
        for (int j = 0; j < 8; ++j) {
          acc[i][j] = fmaf(qv[i].x, kv[j].x, acc[i][j]);
          acc[i][j] = fmaf(qv[i].y, kv[j].y, acc[i][j]);
          acc[i][j] = fmaf(qv[i].z, kv[j].z, acc[i][j]);
          acc[i][j] = fmaf(qv[i].w, kv[j].w, acc[i][j]);
        }
    }

    if (c0 == cbeg) {
      // ---- self-seed threshold from tile 0 (verified construction) ----
      float tmax = -FLT_MAX;
      for (int i = 0; i < 8; ++i) {
        const int rr = ry + 16 * i;
        if (rr >= nrows) continue;
        for (int j = 0; j < 8; ++j) {
          const int cc = cy + 16 * j;
          if (cc >= ncols) continue;
          tmax = fmaxf(tmax, acc[i][j] * 0.125f);
        }
      }
      smax[tid] = tmax;
      __syncthreads();
      for (int k2 = 2; k2 <= 256; k2 <<= 1)
        for (int j2 = k2 >> 1; j2 >= 1; j2 >>= 1) {
          if (tid < 128) {
            const int i = ((tid & ~(j2 - 1)) << 1) | (tid & (j2 - 1));
            const int p = i | j2;
            const bool desc = ((i & k2) == 0);
            const float vi = smax[i], vp = smax[p];
            const bool sw = desc ? (vp > vi) : (vi > vp);
            if (sw) { smax[i] = vp; smax[p] = vi; }
          }
          __syncthreads();
        }
      if (tid == 0 && smax[KK - 1] > -FLT_MAX) thresh = smax[KK - 1] - MARGIN;
      __syncthreads();
    }

    // wave-granular all-or-nothing emission; overflow -> compact + retry
    bool pushed = false;
    for (int attempt = 0; attempt < 8; ++attempt) {
      const float th = thresh;
      int nloc = 0;
      for (int i = 0; i < 8; ++i) {
        const int rr = ry + 16 * i;
        if (rr >= nrows) continue;
        for (int j = 0; j < 8; ++j) {
          const int cc = cy + 16 * j;
          if (cc >= ncols) continue;
          if (acc[i][j] * 0.125f >= th) nloc++;
        }
      }
      int incl = nloc;
      for (int off = 1; off < 64; off <<= 1) {
        int t2 = __shfl_up(incl, off);
        if (lane >= off) incl += t2;
      }
      const int wtot = __shfl(incl, 63);
      if (!pushed) {
        if (wtot == 0) {
          pushed = true;
        } else {
          int wbase = 0;
          if (lane == 63) {
            wbase = atomicAdd(&cnt_sh, wtot);
            if (wbase + wtot > CAP) { atomicAdd(&cnt_sh, -wtot); wbase = -1; ovf = 1; }
          }
          wbase = __shfl(wbase, 63);
          if (wbase >= 0) {
            int sl = wbase + incl - nloc;
            for (int i = 0; i < 8; ++i) {
              const int rr = ry + 16 * i;
              if (rr >= nrows) continue;
              for (int j = 0; j < 8; ++j) {
                const int cc = cy + 16 * j;
                if (cc >= ncols) continue;
                const float s = acc[i][j] * 0.125f;
                if (s >= th) {
                  cval[sl] = s;
                  cidx[sl] = spos_r[rr] * SL + spos_c[cc];
                  ++sl;
                }
              }
            }
            pushed = true;
          }
        }
      }
      __syncthreads();
      if (ovf == 0) break;
      // ---- compaction (cold path, verified): sort fp32 buffer, raise thresh ----
      {
        const int n = cnt_sh;
        for (int j = n + tid; j < CAP; j += 256) { cval[j] = -FLT_MAX; cidx[j] = INT_MAX; }
        __syncthreads();
        for (int k2 = 2; k2 <= CAP; k2 <<= 1)
          for (int j2 = k2 >> 1; j2 >= 1; j2 >>= 1) {
            const int i = ((tid & ~(j2 - 1)) << 1) | (tid & (j2 - 1));
            const int p = i | j2;
            const bool desc = ((i & k2) == 0);
            const float vi = cval[i], vp = cval[p];
            const int ii = cidx[i], ip = cidx[p];
            const bool sw = desc ? cgt32(vp, ip, vi, ii) : cgt32(vi, ii, vp, ip);
            if (sw) { cval[i] = vp; cidx[i] = ip; cval[p] = vi; cidx[p] = ii; }
            __syncthreads();
          }
        const float t64 = cval[KK - 1];
        const float nth = (t64 > -FLT_MAX) ? (t64 - MARGIN) : thresh;
        for (int j = tid; j < CAP; j += 256) {
          const bool in = (cidx[j] != INT_MAX) && (cval[j] >= nth);
          const bool nx = (j + 1 < CAP) && (cidx[j + 1] != INT_MAX) && (cval[j + 1] >= nth);
          if (in && !nx) mcnt = j + 1;
          if (j == 0 && !in) mcnt = 0;
        }
        __syncthreads();
        if (tid == 0) { thresh = nth; cnt_sh = mcnt; ovf = 0; }
        __syncthreads();
      }
    }
    __syncthreads();  // protect sK/spos_c restage
  }

  // ---- fp64 refine (8 threads/survivor, verified) ----
  const int n = cnt_sh;
  double* rval = (double*)sQ;  // alias: sQ dead after scoring
  for (int base2 = 0; base2 < n; base2 += 32) {
    const int s = base2 + (tid >> 3);
    double p = 0;
    if (s < n) {
      const int fi = cidx[s];
      const int orow = fi >> 11, ocol = fi & (SL - 1);
      const float* qr = Q + ((size_t)b * SL + orow) * PP + (tid & 7) * 8;
      const float* kr = K + ((size_t)b * SL + ocol) * PP + (tid & 7) * 8;
#pragma unroll
      for (int e = 0; e < 8; ++e) p = fma((double)qr[e], (double)kr[e], p);
    }
    p += __shfl_down(p, 4);
    p += __shfl_down(p, 2);
    p += __shfl_down(p, 1);
    if (((tid & 7) == 0) && s < n) rval[s] = p * 0.125;
  }
  // ---- adaptive LDS bitonic (verified) + top-64 out ----
  int np2 = KK;
  while (np2 < n) np2 <<= 1;  // n <= CAP
  for (int j = n + tid; j < np2; j += 256) { rval[j] = -DBL_MAX; cidx[j] = INT_MAX; }
  __syncthreads();
  for (int k2 = 2; k2 <= np2; k2 <<= 1)
    for (int j2 = k2 >> 1; j2 >= 1; j2 >>= 1) {
      if (tid < (np2 >> 1)) {
        const int i = ((tid & ~(j2 - 1)) << 1) | (tid & (j2 - 1));
        const int p = i | j2;
        const bool desc = ((i & k2) == 0);
        const double vi = rval[i], vp = rval[p];
        const int ii = cidx[i], ip = cidx[p];
        const bool sw = desc ? cgt64(vp, ip, vi, ii) : cgt64(vi, ii, vp, ip);
        if (sw) { rval[i] = vp; cidx[i] = ip; rval[p] = vi; cidx[p] = ii; }
      }
      __syncthreads();
    }
  if (tid < KK) { chv[tid] = rval[tid]; chi[tid] = cidx[tid]; }
}

// R11/R12-VERIFIED VERBATIM. 64-way merge of sorted lists, fp64 softmax, outputs.
__global__ __launch_bounds__(256) void merge_kernel(
    const double* __restrict__ chunk_val, const int* __restrict__ chunk_idx,
    float* __restrict__ out) {
  __shared__ double sval[NSLOT * 16];
  __shared__ int sidx[NSLOT * 16];
  const int b = blockIdx.x, tid = threadIdx.x;
  const double* vb = chunk_val + (size_t)b * NSLOT * KK;
  const int* ib = chunk_idx + (size_t)b * NSLOT * KK;
  for (int t = tid; t < NSLOT * 16; t += 256) {
    const int list = t >> 4, e = t & 15;
    sval[t] = vb[list * KK + e];
    sidx[t] = ib[list * KK + e];
  }
  __syncthreads();
  if (tid < 64) {
    const int lane = tid;
    int hp = 0;
    double cur = sval[lane * 16];
    int curi = sidx[lane * 16];
    double myv = -DBL_MAX; int myi = INT_MAX;
    for (int k = 0; k < KK; ++k) {
      double bv = cur; int bi = curi; int bg = lane;
      for (int off2 = 32; off2 > 0; off2 >>= 1) {
        const double v2 = __shfl_down(bv, off2);
        const int i2 = __shfl_down(bi, off2);
        const int g2 = __shfl_down(bg, off2);
        if (cgt64(v2, i2, bv, bi)) { bv = v2; bi = i2; bg = g2; }
      }
      bv = __shfl(bv, 0); bi = __shfl(bi, 0); bg = __shfl(bg, 0);
      if (bg == lane) {
        const int h = ++hp;
        if (h < 16) { cur = sval[lane * 16 + h]; curi = sidx[lane * 16 + h]; }
        else if (h < KK) { cur = vb[lane * KK + h]; curi = ib[lane * KK + h]; }
        else { cur = -DBL_MAX; curi = INT_MAX; }
      }
      if (lane == k) { myv = bv; myi = bi; }
    }
    const double m = __shfl(myv, 0);
    double e = (myi == INT_MAX || myv == -DBL_MAX) ? 0.0 : exp(myv - m);
    double s = e;
    for (int off2 = 32; off2 > 0; off2 >>= 1) s += __shfl_down(s, off2);
    s = __shfl(s, 0);
    if (s <= 0.0) s = 1.0;
    const double w = e / s;
    int row = 0, col = 0;
    if (myi != INT_MAX) { row = myi >> 11; col = myi & (SL - 1); }
    float* oidx = out;
    float* owt = out + (size_t)NB * KK * 2;
    oidx[((size_t)b * KK + lane) * 2 + 0] = (float)row;
    oidx[((size_t)b * KK + lane) * 2 + 1] = (float)col;
    owt[(size_t)b * KK + lane] = (float)w;
  }
}

}  // namespace

extern "C" void kernel_launch(void* const* d_in, const int* in_sizes, int n_in,
                              void* d_out, int out_size, void* d_ws, size_t ws_size,
                              hipStream_t stream) {
  const float* x = (const float*)d_in[0];
  const void* mask_raw = d_in[1];
  const float* Wq = (const float*)d_in[2];
  const float* bq = (const float*)d_in[3];
  const float* Wk = (const float*)d_in[4];
  const float* bk = (const float*)d_in[5];
  float* out = (float*)d_out;

  char* ws = (char*)d_ws;
  const size_t qk = (size_t)NB * SL * PP;  // 1,048,576 elems
  float* Q = (float*)ws;                                            // 4 MB
  float* K = (float*)(ws + qk * 4);                                 // 4 MB
  size_t off = qk * 8;
  double* chunk_val = (double*)(ws + off); off += (size_t)NB * NSLOT * KK * 8;  // 256 KB
  int* chunk_idx = (int*)(ws + off);       off += (size_t)NB * NSLOT * KK * 4;  // 128 KB
  int* pos = (int*)(ws + off);             off += (size_t)NB * SL * 4;          // 64 KB
  int* cntv = (int*)(ws + off);            // total ~8.45 MB

  proj_compact_kernel<<<NPROJ + NB, 256, 0, stream>>>(
      x, mask_raw, Wq, bq, Wk, bk, Q, K, pos, cntv);
  score_kernel<<<dim3(NSTRIP, CSPLIT, NB), 256, 0, stream>>>(
      Q, K, pos, cntv, chunk_val, chunk_idx);
  merge_kernel<<<NB, 256, 0, stream>>>(chunk_val, chunk_idx, out);
}